// Round 1
// baseline (872.195 us; speedup 1.0000x reference)
//
#include <hip/hip_runtime.h>
#include <math.h>

#ifndef M_PI
#define M_PI 3.14159265358979323846
#endif

// Problem shapes (fixed)
//  x:   [64,1024,14,14]  w1:[256,1024,1,1] w2:[256,256,3,3] w3:[1024,256,1,1]
#define HW   196
#define NB   64
#define CIN1 1024
#define CP   256
#define K2   2304           // 256*9
#define NCOL 12544          // NB*HW

// ---- workspace layout (float offsets). out3 lives in d_out. ----
static const size_t OF_OUT1 = 0;            // 3,211,264 floats
static const size_t OF_OUT2 = 3211264;      // 3,211,264
static const size_t OF_WQ1  = 6422528;      // 262,144
static const size_t OF_WQ2  = 6684672;      // 589,824
static const size_t OF_WQ3  = 7274496;      // 262,144
static const size_t OF_ST   = 7536640;      // 8,192 stats floats -> total ~30.2 MB

// stats region indices
//  [0..7]   enc min/max (uint) for x,w1,w2,w3
//  [8..19]  (mn,scale,pad) for x,w1,w2,w3
//  [20,21]  q1 mn/scale   [23,24] q2   [26,27] q3
//  stage1: mean@64 sg@320 mn@576 mx@832 sum@1088      (256 each)
//  stage2: mean@1344 sg@1600 mn@1856 mx@2112 sum@2368 (256 each)
//  stage3: mean@2624 sg@3648 mn@4672 mx@5696 sum@6720 (1024 each)

__device__ __forceinline__ unsigned encf(float f) {
    unsigned u = __float_as_uint(f);
    return (u & 0x80000000u) ? ~u : (u | 0x80000000u);
}
__device__ __forceinline__ float decf(unsigned u) {
    return (u & 0x80000000u) ? __uint_as_float(u & 0x7FFFFFFFu) : __uint_as_float(~u);
}
// fake_quant forward: round(clip((v-mn)/scale,0,255))*scale+mn   (rintf = half-to-even, matches jnp.round)
__device__ __forceinline__ float fqv(float v, float mn, float sc) {
    float t = (v - mn) / sc;
    t = fminf(fmaxf(t, 0.0f), 255.0f);
    return rintf(t) * sc + mn;
}

// ---------- init enc slots ----------
__global__ __launch_bounds__(64) void k_init(unsigned* su) {
    int t = threadIdx.x;
    if (t < 8) su[t] = (t & 1) ? 0u : 0xFFFFFFFFu;
}

// ---------- global min/max (float4 grid-stride) ----------
__global__ __launch_bounds__(256) void k_minmax(const float4* __restrict__ p, int n4, unsigned* outu) {
    float mn = INFINITY, mx = -INFINITY;
    int stride = gridDim.x * blockDim.x;
    for (int i = blockIdx.x * blockDim.x + threadIdx.x; i < n4; i += stride) {
        float4 v = p[i];
        mn = fminf(mn, fminf(fminf(v.x, v.y), fminf(v.z, v.w)));
        mx = fmaxf(mx, fmaxf(fmaxf(v.x, v.y), fmaxf(v.z, v.w)));
    }
    for (int o = 32; o; o >>= 1) {
        mn = fminf(mn, __shfl_down(mn, o, 64));
        mx = fmaxf(mx, __shfl_down(mx, o, 64));
    }
    __shared__ float smn[4], smx[4];
    int lane = threadIdx.x & 63, w = threadIdx.x >> 6;
    if (lane == 0) { smn[w] = mn; smx[w] = mx; }
    __syncthreads();
    if (threadIdx.x == 0) {
        for (int i = 1; i < 4; i++) { mn = fminf(mn, smn[i]); mx = fmaxf(mx, smx[i]); }
        atomicMin(&outu[0], encf(mn));
        atomicMax(&outu[1], encf(mx));
    }
}

// ---------- decode min/max -> (mn, scale) for x,w1,w2,w3 ----------
__global__ __launch_bounds__(64) void k_fqparams(const unsigned* su, float* sf) {
    int t = threadIdx.x;
    if (t < 4) {
        float mn = decf(su[2 * t]), mx = decf(su[2 * t + 1]);
        sf[8 + 3 * t]     = mn;
        sf[8 + 3 * t + 1] = fmaxf((mx - mn) / 255.0f, 1e-8f);
    }
}

// ---------- quantize weights into ws ----------
__global__ __launch_bounds__(256) void k_qw(const float* __restrict__ w1, const float* __restrict__ w2,
                                            const float* __restrict__ w3, const float* __restrict__ sf,
                                            float* __restrict__ q1, float* __restrict__ q2, float* __restrict__ q3) {
    int i = blockIdx.x * blockDim.x + threadIdx.x;
    int str = gridDim.x * blockDim.x;
    for (; i < 1114112; i += str) {
        if (i < 262144)       q1[i] = fqv(w1[i], sf[11], sf[12]);
        else if (i < 851968)  q2[i - 262144] = fqv(w2[i - 262144], sf[14], sf[15]);
        else                  q3[i - 851968] = fqv(w3[i - 851968], sf[17], sf[18]);
    }
}

// ---------- 1x1 conv as implicit GEMM: out[n][co][hw] = sum_ci A[co][ci]*B[n][ci][hw] ----------
// grid (196 col tiles, Cout/64), block 256, 64x64 tile, 4x4 per thread
template <int CIN, bool QB>
__global__ __launch_bounds__(256) void k_conv1x1(const float* __restrict__ Bsrc, const float* __restrict__ A,
                                                 const float* __restrict__ sf, float* __restrict__ out, int Cout) {
    __shared__ float As[16][64];
    __shared__ float Bs[16][64];
    int tid = threadIdx.x;
    int tx = tid & 15, ty = tid >> 4;
    int colbase = blockIdx.x * 64, row0 = blockIdx.y * 64;
    float acc[4][4] = {};
    float bmn = 0.f, bsc = 1.f;
    if (QB) { bmn = sf[8]; bsc = sf[9]; }

    int a_co = tid >> 2, a_k = (tid & 3) * 4;       // A staging: float4 along k
    int jloc = tid & 63, kb = (tid >> 6) * 4;       // B staging: coalesced along j
    int j = colbase + jloc;
    int n = j / 196, hw = j - n * 196;
    size_t bbase = (size_t)n * (CIN * 196) + hw;

    for (int k0 = 0; k0 < CIN; k0 += 16) {
        float4 av = *(const float4*)&A[(size_t)(row0 + a_co) * CIN + k0 + a_k];
        As[a_k + 0][a_co] = av.x; As[a_k + 1][a_co] = av.y;
        As[a_k + 2][a_co] = av.z; As[a_k + 3][a_co] = av.w;
#pragma unroll
        for (int i = 0; i < 4; i++) {
            float v = Bsrc[bbase + (size_t)(k0 + kb + i) * 196];
            if (QB) v = fqv(v, bmn, bsc);
            Bs[kb + i][jloc] = v;
        }
        __syncthreads();
        float af[4], bf[4];
#pragma unroll
        for (int k = 0; k < 16; k++) {
            *(float4*)af = *(const float4*)&As[k][ty * 4];
            *(float4*)bf = *(const float4*)&Bs[k][tx * 4];
#pragma unroll
            for (int i = 0; i < 4; i++)
#pragma unroll
                for (int jj = 0; jj < 4; jj++) acc[i][jj] += af[i] * bf[jj];
        }
        __syncthreads();
    }
#pragma unroll
    for (int i = 0; i < 4; i++) {
        int r = row0 + ty * 4 + i;
#pragma unroll
        for (int jj = 0; jj < 4; jj++) {
            int jc = colbase + tx * 4 + jj;
            int nn = jc / 196, hh = jc - nn * 196;
            out[(size_t)nn * (Cout * 196) + (size_t)r * 196 + hh] = acc[i][jj];
        }
    }
}

// ---------- 3x3 pad1 conv as implicit GEMM, K = 256*9 ----------
__global__ __launch_bounds__(256) void k_conv3x3(const float* __restrict__ z, const float* __restrict__ A,
                                                 float* __restrict__ out) {
    __shared__ float As[16][64];
    __shared__ float Bs[16][64];
    int tid = threadIdx.x;
    int tx = tid & 15, ty = tid >> 4;
    int colbase = blockIdx.x * 64, row0 = blockIdx.y * 64;
    float acc[4][4] = {};

    int a_co = tid >> 2, a_k = (tid & 3) * 4;
    int jloc = tid & 63, kb = (tid >> 6) * 4;
    int j = colbase + jloc;
    int n = j / 196, hw = j - n * 196;
    int h = hw / 14, w = hw - h * 14;
    size_t nbase = (size_t)n * (256 * 196);

    for (int k0 = 0; k0 < K2; k0 += 16) {
        float4 av = *(const float4*)&A[(size_t)(row0 + a_co) * K2 + k0 + a_k];
        As[a_k + 0][a_co] = av.x; As[a_k + 1][a_co] = av.y;
        As[a_k + 2][a_co] = av.z; As[a_k + 3][a_co] = av.w;
#pragma unroll
        for (int i = 0; i < 4; i++) {
            int kk = k0 + kb + i;
            int ci = kk / 9, p = kk - ci * 9;
            int r = p / 3, s = p - r * 3;
            int hh = h + r - 1, ww = w + s - 1;
            float v = 0.f;
            if (hh >= 0 && hh < 14 && ww >= 0 && ww < 14)
                v = z[nbase + (size_t)ci * 196 + hh * 14 + ww];
            Bs[kb + i][jloc] = v;
        }
        __syncthreads();
        float af[4], bf[4];
#pragma unroll
        for (int k = 0; k < 16; k++) {
            *(float4*)af = *(const float4*)&As[k][ty * 4];
            *(float4*)bf = *(const float4*)&Bs[k][tx * 4];
#pragma unroll
            for (int i = 0; i < 4; i++)
#pragma unroll
                for (int jj = 0; jj < 4; jj++) acc[i][jj] += af[i] * bf[jj];
        }
        __syncthreads();
    }
#pragma unroll
    for (int i = 0; i < 4; i++) {
        int r = row0 + ty * 4 + i;
#pragma unroll
        for (int jj = 0; jj < 4; jj++) {
            int jc = colbase + tx * 4 + jj;
            int nn = jc / 196, hh = jc - nn * 196;
            out[(size_t)nn * (256 * 196) + (size_t)r * 196 + hh] = acc[i][jj];
        }
    }
}

// ---------- per-channel sum/min/max over (N,H,W) ----------
__global__ __launch_bounds__(256) void k_chstats(const float* __restrict__ buf, int C,
                                                 float* sum_o, float* mn_o, float* mx_o) {
    int c = blockIdx.x, tid = threadIdx.x;
    float sm = 0.f, mn = INFINITY, mx = -INFINITY;
    for (int n = 0; n < NB; n++) {
        const float* p = buf + (size_t)n * C * 196 + (size_t)c * 196;
        for (int hwp = tid; hwp < 196; hwp += 256) {
            float v = p[hwp];
            sm += v; mn = fminf(mn, v); mx = fmaxf(mx, v);
        }
    }
    for (int o = 32; o; o >>= 1) {
        sm += __shfl_down(sm, o, 64);
        mn = fminf(mn, __shfl_down(mn, o, 64));
        mx = fmaxf(mx, __shfl_down(mx, o, 64));
    }
    __shared__ float s1[4], s2[4], s3[4];
    int lane = tid & 63, w = tid >> 6;
    if (lane == 0) { s1[w] = sm; s2[w] = mn; s3[w] = mx; }
    __syncthreads();
    if (tid == 0) {
        for (int i = 1; i < 4; i++) { sm += s1[i]; mn = fminf(mn, s2[i]); mx = fmaxf(mx, s3[i]); }
        sum_o[c] = sm; mn_o[c] = mn; mx_o[c] = mx;
    }
}

// ---------- finalize range_norm: per-channel (mean, sg) + fq params of normalized tensor ----------
__global__ __launch_bounds__(256) void k_finnorm(int C, const float* __restrict__ gamma, const float* __restrict__ beta,
                                                 const float* __restrict__ sum_i, const float* __restrict__ mn_i,
                                                 const float* __restrict__ mx_i, float* mean_o, float* sg_o,
                                                 float* qp, float scale_fix) {
    int tid = threadIdx.x;
    int lane = tid & 63, w = tid >> 6;
    __shared__ float sa[4], sb[4];
    // gamma min/max
    float gmn = INFINITY, gmx = -INFINITY;
    for (int c = tid; c < C; c += 256) { float g = gamma[c]; gmn = fminf(gmn, g); gmx = fmaxf(gmx, g); }
    for (int o = 32; o; o >>= 1) { gmn = fminf(gmn, __shfl_down(gmn, o, 64)); gmx = fmaxf(gmx, __shfl_down(gmx, o, 64)); }
    if (lane == 0) { sa[w] = gmn; sb[w] = gmx; }
    __syncthreads();
    gmn = fminf(fminf(sa[0], sa[1]), fminf(sa[2], sa[3]));
    gmx = fmaxf(fmaxf(sb[0], sb[1]), fmaxf(sb[2], sb[3]));
    float gsc = fmaxf((gmx - gmn) / 255.0f, 1e-8f);
    __syncthreads();
    // per-channel affine + bounds of normalized output
    float qmn = INFINITY, qmx = -INFINITY;
    for (int c = tid; c < C; c += 256) {
        float mean = sum_i[c] / 12544.0f;
        float rng  = mx_i[c] - mn_i[c];
        float qg   = fqv(gamma[c], gmn, gsc);
        float s    = qg / (rng * scale_fix + 1e-5f);
        mean_o[c] = mean; sg_o[c] = s;
        float b  = beta[c];
        float lo = (mn_i[c] - mean) * s + b;
        float hi = (mx_i[c] - mean) * s + b;
        qmn = fminf(qmn, fminf(lo, hi));
        qmx = fmaxf(qmx, fmaxf(lo, hi));
    }
    for (int o = 32; o; o >>= 1) { qmn = fminf(qmn, __shfl_down(qmn, o, 64)); qmx = fmaxf(qmx, __shfl_down(qmx, o, 64)); }
    if (lane == 0) { sa[w] = qmn; sb[w] = qmx; }
    __syncthreads();
    if (tid == 0) {
        qmn = fminf(fminf(sa[0], sa[1]), fminf(sa[2], sa[3]));
        qmx = fmaxf(fmaxf(sb[0], sb[1]), fmaxf(sb[2], sb[3]));
        qp[0] = qmn;
        qp[1] = fmaxf((qmx - qmn) / 255.0f, 1e-8f);
    }
}

// ---------- in-place normalize + fake_quant (z = fq(norm(v))) ----------
__global__ __launch_bounds__(256) void k_normq(float* __restrict__ buf, int Cmask,
                                               const float* __restrict__ mean, const float* __restrict__ sg,
                                               const float* __restrict__ beta, const float* __restrict__ qp, int n4) {
    float qmn = qp[0], qsc = qp[1];
    float4* p = (float4*)buf;
    int i = blockIdx.x * blockDim.x + threadIdx.x;
    int str = gridDim.x * blockDim.x;
    for (; i < n4; i += str) {
        int e = i * 4;
        int c = (e / 196) & Cmask;      // 196 % 4 == 0 -> same channel across the float4
        float m = mean[c], s = sg[c], b = beta[c];
        float4 v = p[i];
        v.x = fqv((v.x - m) * s + b, qmn, qsc);
        v.y = fqv((v.y - m) * s + b, qmn, qsc);
        v.z = fqv((v.z - m) * s + b, qmn, qsc);
        v.w = fqv((v.w - m) * s + b, qmn, qsc);
        p[i] = v;
    }
}

// ---------- final: out = fq(x) + fq(norm3(out3)); out3 already lives in d_out (in-place) ----------
__global__ __launch_bounds__(256) void k_final(const float* __restrict__ x, float* __restrict__ out,
                                               const float* __restrict__ mean, const float* __restrict__ sg,
                                               const float* __restrict__ beta, const float* __restrict__ sf,
                                               const float* __restrict__ qp) {
    float xmn = sf[8], xsc = sf[9];
    float qmn = qp[0], qsc = qp[1];
    const float4* xp = (const float4*)x;
    float4* yp = (float4*)out;
    int n4 = 12845056 / 4;
    int i = blockIdx.x * blockDim.x + threadIdx.x;
    int str = gridDim.x * blockDim.x;
    for (; i < n4; i += str) {
        int e = i * 4;
        int c = (e / 196) & 1023;
        float m = mean[c], s = sg[c], b = beta[c];
        float4 xv = xp[i], ov = yp[i], r;
        r.x = fqv(xv.x, xmn, xsc) + fqv((ov.x - m) * s + b, qmn, qsc);
        r.y = fqv(xv.y, xmn, xsc) + fqv((ov.y - m) * s + b, qmn, qsc);
        r.z = fqv(xv.z, xmn, xsc) + fqv((ov.z - m) * s + b, qmn, qsc);
        r.w = fqv(xv.w, xmn, xsc) + fqv((ov.w - m) * s + b, qmn, qsc);
        yp[i] = r;
    }
}

extern "C" void kernel_launch(void* const* d_in, const int* in_sizes, int n_in,
                              void* d_out, int out_size, void* d_ws, size_t ws_size,
                              hipStream_t stream) {
    const float* x  = (const float*)d_in[0];
    const float* w1 = (const float*)d_in[1];
    const float* g1 = (const float*)d_in[2];
    const float* b1 = (const float*)d_in[3];
    const float* w2 = (const float*)d_in[4];
    const float* g2 = (const float*)d_in[5];
    const float* b2 = (const float*)d_in[6];
    const float* w3 = (const float*)d_in[7];
    const float* g3 = (const float*)d_in[8];
    const float* b3 = (const float*)d_in[9];
    float* out = (float*)d_out;

    float* W    = (float*)d_ws;
    float* out1 = W + OF_OUT1;
    float* out2 = W + OF_OUT2;
    float* wq1  = W + OF_WQ1;
    float* wq2  = W + OF_WQ2;
    float* wq3  = W + OF_WQ3;
    float* S    = W + OF_ST;
    unsigned* Su = (unsigned*)S;

    const float scale_fix =
        (float)((0.5 * 0.35) * (1.0 + sqrt(M_PI * log(4.0))) / sqrt(2.0 * log(12544.0)));

    // ---- fq params for x, w1, w2, w3 ----
    k_init<<<1, 64, 0, stream>>>(Su);
    k_minmax<<<1024, 256, 0, stream>>>((const float4*)x,  12845056 / 4, Su + 0);
    k_minmax<<<64,   256, 0, stream>>>((const float4*)w1, 262144 / 4,  Su + 2);
    k_minmax<<<128,  256, 0, stream>>>((const float4*)w2, 589824 / 4,  Su + 4);
    k_minmax<<<64,   256, 0, stream>>>((const float4*)w3, 262144 / 4,  Su + 6);
    k_fqparams<<<1, 64, 0, stream>>>(Su, S);
    k_qw<<<1024, 256, 0, stream>>>(w1, w2, w3, S, wq1, wq2, wq3);

    // ---- conv1 (fq(x) on the fly) -> out1 ----
    k_conv1x1<CIN1, true><<<dim3(196, 4), 256, 0, stream>>>(x, wq1, S, out1, CP);

    // ---- range_norm1 + fq -> z1 (in place in out1) ----
    k_chstats<<<CP, 256, 0, stream>>>(out1, CP, S + 1088, S + 576, S + 832);
    k_finnorm<<<1, 256, 0, stream>>>(CP, g1, b1, S + 1088, S + 576, S + 832, S + 64, S + 320, S + 20, scale_fix);
    k_normq<<<1024, 256, 0, stream>>>(out1, CP - 1, S + 64, S + 320, b1, S + 20, 3211264 / 4);

    // ---- conv2 -> out2 ----
    k_conv3x3<<<dim3(196, 4), 256, 0, stream>>>(out1, wq2, out2);

    // ---- range_norm2 + fq -> z2 (in place in out2) ----
    k_chstats<<<CP, 256, 0, stream>>>(out2, CP, S + 2368, S + 1856, S + 2112);
    k_finnorm<<<1, 256, 0, stream>>>(CP, g2, b2, S + 2368, S + 1856, S + 2112, S + 1344, S + 1600, S + 23, scale_fix);
    k_normq<<<1024, 256, 0, stream>>>(out2, CP - 1, S + 1344, S + 1600, b2, S + 23, 3211264 / 4);

    // ---- conv3 -> out3 (stored in d_out) ----
    k_conv1x1<CP, false><<<dim3(196, 16), 256, 0, stream>>>(out2, wq3, S, out, CIN1);

    // ---- range_norm3 stats + final fused fq(x)+fq(norm3(out3)) (in place in d_out) ----
    k_chstats<<<CIN1, 256, 0, stream>>>(out, CIN1, S + 6720, S + 4672, S + 5696);
    k_finnorm<<<1, 256, 0, stream>>>(CIN1, g3, b3, S + 6720, S + 4672, S + 5696, S + 2624, S + 3648, S + 26, scale_fix);
    k_final<<<2048, 256, 0, stream>>>(x, out, S + 2624, S + 3648, b3, S, S + 26);
}

// Round 2
// 460.147 us; speedup vs baseline: 1.8955x; 1.8955x over previous
//
#include <hip/hip_runtime.h>
#include <math.h>

#ifndef M_PI
#define M_PI 3.14159265358979323846
#endif

// Shapes: x [64,1024,14,14]; w1 [256,1024]; w2 [256,256,3,3]; w3 [1024,256]
#define NB   64
#define CP   256
#define NCOL 12544

typedef __attribute__((ext_vector_type(8))) short short8;
typedef __attribute__((ext_vector_type(4))) float f32x4;

// ---------------- workspace layout (float offsets) ----------------
static const size_t OF_OUT = 0;            // shared fp32 conv out (3,211,264 f) out1 then out2
static const size_t OF_XC  = 3211264;      // xcode NHWC bf16 region (6,422,528 f worth)
static const size_t OF_Z1P = 3211264;      // z1 padded codes [64][16][16][256] bf16 (2,097,152 f) - reuses XC after conv1
static const size_t OF_Z2C = 5308416;      // z2 codes [64][196][256] bf16 (1,605,632 f)
static const size_t OF_WQ1 = 9633792;      // [256][1024] bf16 codes (131,072 f)
static const size_t OF_WQ2 = 9764864;      // [256][2304] bf16 codes (294,912 f)
static const size_t OF_WQ3 = 10059776;     // [1024][256] bf16 codes (131,072 f)
static const size_t OF_R1  = 10190848;     // 256
static const size_t OF_R2  = 10191104;     // 256
static const size_t OF_R3  = 10191360;     // 1024
static const size_t OF_T2  = 10192384;     // 256*8 tap aggregates
static const size_t OF_CX  = 10194432;     // 12544 colsum of xcode
static const size_t OF_U2  = 10206976;     // 16384 per-(n,hp,wp) chansum of z1p
static const size_t OF_V2  = 10223360;     // 12544 9-tap sums
static const size_t OF_CZ  = 10235904;     // 12544 colsum z2
static const size_t OF_ST  = 10248448;     // stats (8192 f)
// stats offsets (same as round 1):
//  [0..7] enc min/max x,w1,w2,w3 ; [8..19] (mn,scale,_) per tensor
//  [20,21] q1 ; [23,24] q2 ; [26,27] q3
//  st1: mean@64 sg@320 mn@576 mx@832 sum@1088
//  st2: mean@1344 sg@1600 mn@1856 mx@2112 sum@2368
//  st3: mean@2624 sg@3648 mn@4672 mx@5696 sum@6720

__device__ __forceinline__ unsigned encf(float f) {
    unsigned u = __float_as_uint(f);
    return (u & 0x80000000u) ? ~u : (u | 0x80000000u);
}
__device__ __forceinline__ float decf(unsigned u) {
    return (u & 0x80000000u) ? __uint_as_float(u & 0x7FFFFFFFu) : __uint_as_float(~u);
}
__device__ __forceinline__ float fqv(float v, float mn, float sc) {
    float t = (v - mn) / sc;
    t = fminf(fmaxf(t, 0.0f), 255.0f);
    return rintf(t) * sc + mn;
}
// centered code (as float, integer-valued in [-128,127])
__device__ __forceinline__ float codef(float v, float mn, float sc) {
    float t = (v - mn) / sc;
    t = fminf(fmaxf(t, 0.0f), 255.0f);
    return rintf(t) - 128.0f;
}
__device__ __forceinline__ unsigned short f2bf(float f) { return (unsigned short)(__float_as_uint(f) >> 16); }
__device__ __forceinline__ float bf2f(unsigned short u) { return __uint_as_float(((unsigned)u) << 16); }

__device__ __forceinline__ void glds16(const void* g, void* l) {
    __builtin_amdgcn_global_load_lds((const __attribute__((address_space(1))) unsigned int*)g,
                                     (__attribute__((address_space(3))) unsigned int*)l, 16, 0, 0);
}

// ---------------- small utility kernels ----------------
__global__ __launch_bounds__(64) void k_init(unsigned* su) {
    int t = threadIdx.x;
    if (t < 8) su[t] = (t & 1) ? 0u : 0xFFFFFFFFu;
}

__global__ __launch_bounds__(256) void k_minmax(const float4* __restrict__ p, int n4, unsigned* outu) {
    float mn = INFINITY, mx = -INFINITY;
    int stride = gridDim.x * blockDim.x;
    for (int i = blockIdx.x * blockDim.x + threadIdx.x; i < n4; i += stride) {
        float4 v = p[i];
        mn = fminf(mn, fminf(fminf(v.x, v.y), fminf(v.z, v.w)));
        mx = fmaxf(mx, fmaxf(fmaxf(v.x, v.y), fmaxf(v.z, v.w)));
    }
    for (int o = 32; o; o >>= 1) {
        mn = fminf(mn, __shfl_down(mn, o, 64));
        mx = fmaxf(mx, __shfl_down(mx, o, 64));
    }
    __shared__ float smn[4], smx[4];
    int lane = threadIdx.x & 63, w = threadIdx.x >> 6;
    if (lane == 0) { smn[w] = mn; smx[w] = mx; }
    __syncthreads();
    if (threadIdx.x == 0) {
        for (int i = 1; i < 4; i++) { mn = fminf(mn, smn[i]); mx = fmaxf(mx, smx[i]); }
        atomicMin(&outu[0], encf(mn));
        atomicMax(&outu[1], encf(mx));
    }
}

__global__ __launch_bounds__(64) void k_fqparams(const unsigned* su, float* sf) {
    int t = threadIdx.x;
    if (t < 4) {
        float mn = decf(su[2 * t]), mx = decf(su[2 * t + 1]);
        sf[8 + 3 * t]     = mn;
        sf[8 + 3 * t + 1] = fmaxf((mx - mn) / 255.0f, 1e-8f);
    }
}

// ---------------- weight code kernels ----------------
__global__ __launch_bounds__(256) void k_wcode11(const float* __restrict__ w, const float* __restrict__ pw,
                                                 unsigned short* __restrict__ wc, float* __restrict__ R, int K) {
    int co = blockIdx.x, t = threadIdx.x;
    float mn = pw[0], s = pw[1];
    float sum = 0.f;
    for (int k = t; k < K; k += 256) {
        float c = codef(w[(size_t)co * K + k], mn, s);
        wc[(size_t)co * K + k] = f2bf(c);
        sum += c;
    }
    for (int o = 32; o; o >>= 1) sum += __shfl_down(sum, o, 64);
    __shared__ float sr[4];
    int lane = t & 63, wv = t >> 6;
    if (lane == 0) sr[wv] = sum;
    __syncthreads();
    if (t == 0) R[co] = sr[0] + sr[1] + sr[2] + sr[3];
}

// w2 [co][ci][9] -> codes [co][p*256+ci], R2[co], T8[co][8]={top,bot,left,right,T0,T2,T6,T8}
__global__ __launch_bounds__(256) void k_wcode33(const float* __restrict__ w, const float* __restrict__ pw,
                                                 unsigned short* __restrict__ wc, float* __restrict__ R,
                                                 float* __restrict__ T8) {
    int co = blockIdx.x, ci = threadIdx.x;
    float mn = pw[0], s = pw[1];
    float tp[9];
#pragma unroll
    for (int p = 0; p < 9; p++) {
        float c = codef(w[((size_t)co * 256 + ci) * 9 + p], mn, s);
        wc[(size_t)co * 2304 + p * 256 + ci] = f2bf(c);
        tp[p] = c;
    }
    __shared__ float red[4][9];
    __shared__ float sT[9];
    int lane = ci & 63, wv = ci >> 6;
#pragma unroll
    for (int p = 0; p < 9; p++) {
        float v = tp[p];
        for (int o = 32; o; o >>= 1) v += __shfl_down(v, o, 64);
        if (lane == 0) red[wv][p] = v;
    }
    __syncthreads();
    if (ci < 9) sT[ci] = red[0][ci] + red[1][ci] + red[2][ci] + red[3][ci];
    __syncthreads();
    if (ci == 0) {
        float T0 = sT[0], T1 = sT[1], T2 = sT[2], T3 = sT[3], T4 = sT[4],
              T5 = sT[5], T6 = sT[6], T7 = sT[7], T8v = sT[8];
        R[co] = T0 + T1 + T2 + T3 + T4 + T5 + T6 + T7 + T8v;
        float* o = &T8[co * 8];
        o[0] = T0 + T1 + T2;   // top (r=0)
        o[1] = T6 + T7 + T8v;  // bot (r=2)
        o[2] = T0 + T3 + T6;   // left (s=0)
        o[3] = T2 + T5 + T8v;  // right (s=2)
        o[4] = T0; o[5] = T2; o[6] = T6; o[7] = T8v;
    }
}

// ---------------- activation code + transpose to NHWC ----------------
// MODE 0: x fp32 NCHW (C=1024, cq chunks) -> plain fq codes, dst [n][hw][1024]
// MODE 1: conv-out fp32 NCHW (C=256) -> norm+fq codes, dst padded [n][16][16][256]
// MODE 2: conv-out fp32 NCHW (C=256) -> norm+fq codes, dst [n][hw][256]
template <int MODE>
__global__ __launch_bounds__(256) void k_code(const float* __restrict__ src, unsigned short* __restrict__ dst,
                                              const float* __restrict__ mean, const float* __restrict__ sg,
                                              const float* __restrict__ beta, const float* __restrict__ qp) {
    __shared__ unsigned short lt[28][264];
    int n = blockIdx.z, hw0 = blockIdx.x * 28, cq = blockIdx.y * 256;
    int t = threadIdx.x;
    const int Csrc = (MODE == 0) ? 1024 : 256;
    float qmn = qp[0], qsc = qp[1];
    const float* sp = src + ((size_t)n * Csrc + cq) * 196 + hw0;
    for (int i = t; i < 7168; i += 256) {
        int c = i / 28, hw = i - c * 28;
        float v = sp[(size_t)c * 196 + hw];
        if (MODE != 0) v = (v - mean[c]) * sg[c] + beta[c];
        lt[hw][c] = f2bf(codef(v, qmn, qsc));
    }
    __syncthreads();
#pragma unroll 4
    for (int i = 0; i < 28; i++) {
        int hw = hw0 + i;
        unsigned short val = lt[i][t];
        size_t da;
        if (MODE == 0) da = ((size_t)n * 196 + hw) * 1024 + cq + t;
        else if (MODE == 1) {
            int h = hw / 14 + 1, w = hw - (hw / 14) * 14 + 1;
            da = (((size_t)n * 16 + h) * 16 + w) * 256 + t;
        } else da = ((size_t)n * 196 + hw) * 256 + t;
        dst[da] = val;
    }
}

// colsum over last dim: Ccol[row] = sum_c codes[row*C+c]
__global__ __launch_bounds__(256) void k_colsum(const unsigned short* __restrict__ Z, float* __restrict__ Ccol,
                                                int C, int rows) {
    int row = blockIdx.x * 4 + (threadIdx.x >> 6);
    int lane = threadIdx.x & 63;
    if (row >= rows) return;
    const unsigned short* p = Z + (size_t)row * C;
    float s = 0.f;
    for (int c = lane; c < C; c += 64) s += bf2f(p[c]);
    for (int o = 32; o; o >>= 1) s += __shfl_down(s, o, 64);
    if (lane == 0) Ccol[row] = s;
}

// V2[j] = 9-tap sum of U2p (padded [n][16][16])
__global__ __launch_bounds__(256) void k_v2(const float* __restrict__ U, float* __restrict__ V) {
    int j = blockIdx.x * 256 + threadIdx.x;
    if (j >= NCOL) return;
    int n = j / 196, hw = j - n * 196, h = hw / 14, w = hw - (hw / 14) * 14;
    const float* u = U + (size_t)n * 256;
    float s = 0.f;
#pragma unroll
    for (int r = 0; r < 3; r++)
#pragma unroll
        for (int c = 0; c < 3; c++) s += u[(h + r) * 16 + (w + c)];
    V[j] = s;
}

// ---------------- MFMA implicit-GEMM conv ----------------
// MI=2 -> BM=64 ; MI=4 -> BM=128. BN=128, BK=32.
// MODE 0: B = [12544][K] codes (K=1024 or 256). MODE 1: B = z1p padded codes, K=2304 (k = p*256+ci).
template <int MI, int MODE>
__global__ __launch_bounds__(256) void k_convmm(const unsigned short* __restrict__ A,
                                                const unsigned short* __restrict__ B,
                                                const float* __restrict__ R, const float* __restrict__ T8,
                                                const float* __restrict__ Cj,
                                                const float* __restrict__ pw, const float* __restrict__ pz,
                                                float* __restrict__ out, int Cout, int K) {
    constexpr int BM = MI * 32;
    __shared__ __align__(16) unsigned short As[BM * 32];
    __shared__ __align__(16) unsigned short Bs[128 * 32];
    int tid = threadIdx.x;
    int lane = tid & 63, wave = tid >> 6;
    int wm = wave >> 1, wn = wave & 1;
    int row0 = blockIdx.y * BM, jb = blockIdx.x * 128;

    // staging: thread covers 16B = 8 codes; sm = row/col in tile, ks8 = k offset
    int sm = tid >> 2, ks8 = (tid & 3) * 8;
    const unsigned short* ga0 = A + (size_t)(row0 + sm) * K + ks8;
    const unsigned short* ga1 = ga0 + (size_t)64 * K;  // used only if MI==4
    unsigned short* la0 = &As[sm * 32 + ks8];
    unsigned short* la1 = &As[(64 + sm) * 32 + ks8];
    unsigned short* lb0 = &Bs[sm * 32 + ks8];
    unsigned short* lb1 = &Bs[(64 + sm) * 32 + ks8];

    int j0 = jb + sm, j1 = jb + sm + 64;
    size_t cb0, cb1;
    if (MODE == 0) {
        cb0 = (size_t)j0 * K + ks8;
        cb1 = (size_t)j1 * K + ks8;
    } else {
        int n0 = j0 / 196, hw0 = j0 - n0 * 196, h0 = hw0 / 14, w0 = hw0 - (hw0 / 14) * 14;
        int n1 = j1 / 196, hw1 = j1 - n1 * 196, h1 = hw1 / 14, w1 = hw1 - (hw1 / 14) * 14;
        cb0 = (((size_t)n0 * 16 + h0) * 16 + w0) * 256 + ks8;
        cb1 = (((size_t)n1 * 16 + h1) * 16 + w1) * 256 + ks8;
    }

    f32x4 acc[MI][4];
#pragma unroll
    for (int mi = 0; mi < MI; mi++)
#pragma unroll
        for (int ni = 0; ni < 4; ni++) acc[mi][ni] = 0.f;

    for (int k0 = 0; k0 < K; k0 += 32) {
        __syncthreads();
        glds16(ga0, la0);
        if (MI == 4) glds16(ga1, la1);
        if (MODE == 0) {
            glds16(B + cb0, lb0);
            glds16(B + cb1, lb1);
            cb0 += 32; cb1 += 32;
        } else {
            int p = k0 >> 8, kin = k0 - (p << 8);
            int rr = p / 3, ss = p - rr * 3;
            size_t add = (size_t)(rr * 16 + ss) * 256 + kin;
            glds16(B + cb0 + add, lb0);
            glds16(B + cb1 + add, lb1);
        }
        ga0 += 32;
        if (MI == 4) ga1 += 32;
        __syncthreads();

        short8 af[MI], bfr[4];
#pragma unroll
        for (int mi = 0; mi < MI; mi++)
            af[mi] = *(const short8*)&As[(wm * (MI * 16) + mi * 16 + (lane & 15)) * 32 + (lane >> 4) * 8];
#pragma unroll
        for (int ni = 0; ni < 4; ni++)
            bfr[ni] = *(const short8*)&Bs[(wn * 64 + ni * 16 + (lane & 15)) * 32 + (lane >> 4) * 8];
#pragma unroll
        for (int mi = 0; mi < MI; mi++)
#pragma unroll
            for (int ni = 0; ni < 4; ni++)
                acc[mi][ni] = __builtin_amdgcn_mfma_f32_16x16x32_bf16(af[mi], bfr[ni], acc[mi][ni], 0, 0, 0);
    }

    // epilogue: value = aw*az*S + aw*bz*(R - PT) + bw*az*Cj + bw*bz*Kvalid
    float aw = pw[1], bw = pw[0] + 128.f * pw[1];
    float az = pz[1], bz = pz[0] + 128.f * pz[1];
    float caa = aw * az, cR = aw * bz, cC = bw * az, cK = bw * bz;
    int colbase = jb + wn * 64 + (lane & 15);
    int rowq = (lane >> 4) * 4;
#pragma unroll
    for (int ni = 0; ni < 4; ni++) {
        int j = colbase + ni * 16;
        int nimg = j / 196, hw = j - nimg * 196;
        float cj = Cj[j];
        float constterm;
        float pt = 0.f, pb = 0.f, pl = 0.f, pr = 0.f, ctl = 0.f, ctr = 0.f, cbl = 0.f, cbr = 0.f;
        if (MODE == 1) {
            int h = hw / 14, w = hw - (hw / 14) * 14;
            pt = (h == 0) ? 1.f : 0.f;  pb = (h == 13) ? 1.f : 0.f;
            pl = (w == 0) ? 1.f : 0.f;  pr = (w == 13) ? 1.f : 0.f;
            ctl = pt * pl; ctr = pt * pr; cbl = pb * pl; cbr = pb * pr;
            float miss = 3.f * (pt + pb + pl + pr) - (ctl + ctr + cbl + cbr);
            constterm = cK * (256.f * (9.f - miss));
        } else {
            constterm = cK * (float)K;
        }
#pragma unroll
        for (int mi = 0; mi < MI; mi++) {
            int co0 = row0 + wm * (MI * 16) + mi * 16 + rowq;
#pragma unroll
            for (int l = 0; l < 4; l++) {
                int co = co0 + l;
                float rsum = R[co];
                if (MODE == 1) {
                    const float* t8 = &T8[co * 8];
                    rsum -= pt * t8[0] + pb * t8[1] + pl * t8[2] + pr * t8[3]
                          - ctl * t8[4] - ctr * t8[5] - cbl * t8[6] - cbr * t8[7];
                }
                out[((size_t)nimg * Cout + co) * 196 + hw] = caa * acc[mi][ni][l] + cR * rsum + cC * cj + constterm;
            }
        }
    }
}

// ---------------- per-channel stats / finalize (unchanged from round 1) ----------------
__global__ __launch_bounds__(256) void k_chstats(const float* __restrict__ buf, int C,
                                                 float* sum_o, float* mn_o, float* mx_o) {
    int c = blockIdx.x, tid = threadIdx.x;
    float sm = 0.f, mn = INFINITY, mx = -INFINITY;
    for (int n = 0; n < NB; n++) {
        const float* p = buf + (size_t)n * C * 196 + (size_t)c * 196;
        for (int hwp = tid; hwp < 196; hwp += 256) {
            float v = p[hwp];
            sm += v; mn = fminf(mn, v); mx = fmaxf(mx, v);
        }
    }
    for (int o = 32; o; o >>= 1) {
        sm += __shfl_down(sm, o, 64);
        mn = fminf(mn, __shfl_down(mn, o, 64));
        mx = fmaxf(mx, __shfl_down(mx, o, 64));
    }
    __shared__ float s1[4], s2[4], s3[4];
    int lane = tid & 63, w = tid >> 6;
    if (lane == 0) { s1[w] = sm; s2[w] = mn; s3[w] = mx; }
    __syncthreads();
    if (tid == 0) {
        for (int i = 1; i < 4; i++) { sm += s1[i]; mn = fminf(mn, s2[i]); mx = fmaxf(mx, s3[i]); }
        sum_o[c] = sm; mn_o[c] = mn; mx_o[c] = mx;
    }
}

__global__ __launch_bounds__(256) void k_finnorm(int C, const float* __restrict__ gamma, const float* __restrict__ beta,
                                                 const float* __restrict__ sum_i, const float* __restrict__ mn_i,
                                                 const float* __restrict__ mx_i, float* mean_o, float* sg_o,
                                                 float* qp, float scale_fix) {
    int tid = threadIdx.x;
    int lane = tid & 63, w = tid >> 6;
    __shared__ float sa[4], sb[4];
    float gmn = INFINITY, gmx = -INFINITY;
    for (int c = tid; c < C; c += 256) { float g = gamma[c]; gmn = fminf(gmn, g); gmx = fmaxf(gmx, g); }
    for (int o = 32; o; o >>= 1) { gmn = fminf(gmn, __shfl_down(gmn, o, 64)); gmx = fmaxf(gmx, __shfl_down(gmx, o, 64)); }
    if (lane == 0) { sa[w] = gmn; sb[w] = gmx; }
    __syncthreads();
    gmn = fminf(fminf(sa[0], sa[1]), fminf(sa[2], sa[3]));
    gmx = fmaxf(fmaxf(sb[0], sb[1]), fmaxf(sb[2], sb[3]));
    float gsc = fmaxf((gmx - gmn) / 255.0f, 1e-8f);
    __syncthreads();
    float qmn = INFINITY, qmx = -INFINITY;
    for (int c = tid; c < C; c += 256) {
        float mean = sum_i[c] / 12544.0f;
        float rng  = mx_i[c] - mn_i[c];
        float qg   = fqv(gamma[c], gmn, gsc);
        float s    = qg / (rng * scale_fix + 1e-5f);
        mean_o[c] = mean; sg_o[c] = s;
        float b  = beta[c];
        float lo = (mn_i[c] - mean) * s + b;
        float hi = (mx_i[c] - mean) * s + b;
        qmn = fminf(qmn, fminf(lo, hi));
        qmx = fmaxf(qmx, fmaxf(lo, hi));
    }
    for (int o = 32; o; o >>= 1) { qmn = fminf(qmn, __shfl_down(qmn, o, 64)); qmx = fmaxf(qmx, __shfl_down(qmx, o, 64)); }
    if (lane == 0) { sa[w] = qmn; sb[w] = qmx; }
    __syncthreads();
    if (tid == 0) {
        qmn = fminf(fminf(sa[0], sa[1]), fminf(sa[2], sa[3]));
        qmx = fmaxf(fmaxf(sb[0], sb[1]), fmaxf(sb[2], sb[3]));
        qp[0] = qmn;
        qp[1] = fmaxf((qmx - qmn) / 255.0f, 1e-8f);
    }
}

__global__ __launch_bounds__(256) void k_final(const float* __restrict__ x, float* __restrict__ out,
                                               const float* __restrict__ mean, const float* __restrict__ sg,
                                               const float* __restrict__ beta, const float* __restrict__ sf,
                                               const float* __restrict__ qp) {
    float xmn = sf[8], xsc = sf[9];
    float qmn = qp[0], qsc = qp[1];
    const float4* xp = (const float4*)x;
    float4* yp = (float4*)out;
    int n4 = 12845056 / 4;
    int i = blockIdx.x * blockDim.x + threadIdx.x;
    int str = gridDim.x * blockDim.x;
    for (; i < n4; i += str) {
        int e = i * 4;
        int c = (e / 196) & 1023;
        float m = mean[c], s = sg[c], b = beta[c];
        float4 xv = xp[i], ov = yp[i], r;
        r.x = fqv(xv.x, xmn, xsc) + fqv((ov.x - m) * s + b, qmn, qsc);
        r.y = fqv(xv.y, xmn, xsc) + fqv((ov.y - m) * s + b, qmn, qsc);
        r.z = fqv(xv.z, xmn, xsc) + fqv((ov.z - m) * s + b, qmn, qsc);
        r.w = fqv(xv.w, xmn, xsc) + fqv((ov.w - m) * s + b, qmn, qsc);
        yp[i] = r;
    }
}

extern "C" void kernel_launch(void* const* d_in, const int* in_sizes, int n_in,
                              void* d_out, int out_size, void* d_ws, size_t ws_size,
                              hipStream_t stream) {
    const float* x  = (const float*)d_in[0];
    const float* w1 = (const float*)d_in[1];
    const float* g1 = (const float*)d_in[2];
    const float* b1 = (const float*)d_in[3];
    const float* w2 = (const float*)d_in[4];
    const float* g2 = (const float*)d_in[5];
    const float* b2 = (const float*)d_in[6];
    const float* w3 = (const float*)d_in[7];
    const float* g3 = (const float*)d_in[8];
    const float* b3 = (const float*)d_in[9];
    float* out = (float*)d_out;

    float* W = (float*)d_ws;
    float* OUT = W + OF_OUT;
    unsigned short* xc   = (unsigned short*)(W + OF_XC);
    unsigned short* z1p  = (unsigned short*)(W + OF_Z1P);
    unsigned short* z2c  = (unsigned short*)(W + OF_Z2C);
    unsigned short* wq1c = (unsigned short*)(W + OF_WQ1);
    unsigned short* wq2c = (unsigned short*)(W + OF_WQ2);
    unsigned short* wq3c = (unsigned short*)(W + OF_WQ3);
    float* R1 = W + OF_R1;  float* R2 = W + OF_R2;  float* R3 = W + OF_R3;
    float* T2 = W + OF_T2;
    float* CX = W + OF_CX;  float* U2 = W + OF_U2;  float* V2 = W + OF_V2;  float* CZ = W + OF_CZ;
    float* S = W + OF_ST;
    unsigned* Su = (unsigned*)S;

    const float scale_fix =
        (float)((0.5 * 0.35) * (1.0 + sqrt(M_PI * log(4.0))) / sqrt(2.0 * log(12544.0)));

    // fq params for x, w1, w2, w3
    k_init<<<1, 64, 0, stream>>>(Su);
    k_minmax<<<1024, 256, 0, stream>>>((const float4*)x,  12845056 / 4, Su + 0);
    k_minmax<<<64,   256, 0, stream>>>((const float4*)w1, 262144 / 4,  Su + 2);
    k_minmax<<<128,  256, 0, stream>>>((const float4*)w2, 589824 / 4,  Su + 4);
    k_minmax<<<64,   256, 0, stream>>>((const float4*)w3, 262144 / 4,  Su + 6);
    k_fqparams<<<1, 64, 0, stream>>>(Su, S);

    // weight codes + reductions
    k_wcode11<<<256,  256, 0, stream>>>(w1, S + 11, wq1c, R1, 1024);
    k_wcode11<<<1024, 256, 0, stream>>>(w3, S + 17, wq3c, R3, 256);
    k_wcode33<<<256,  256, 0, stream>>>(w2, S + 14, wq2c, R2, T2);

    // x -> NHWC codes + colsum
    k_code<0><<<dim3(7, 4, 64), 256, 0, stream>>>(x, xc, S, S, S, S + 8);
    k_colsum<<<3136, 256, 0, stream>>>(xc, CX, 1024, NCOL);

    // conv1 -> OUT (fp32 NCHW)
    k_convmm<2, 0><<<dim3(98, 4), 256, 0, stream>>>(wq1c, xc, R1, nullptr, CX, S + 11, S + 8, OUT, 256, 1024);

    // range_norm1 -> z1 padded codes
    k_chstats<<<256, 256, 0, stream>>>(OUT, 256, S + 1088, S + 576, S + 832);
    k_finnorm<<<1, 256, 0, stream>>>(256, g1, b1, S + 1088, S + 576, S + 832, S + 64, S + 320, S + 20, scale_fix);
    hipMemsetAsync(z1p, 0, (size_t)64 * 16 * 16 * 256 * 2, stream);
    k_code<1><<<dim3(7, 1, 64), 256, 0, stream>>>(OUT, z1p, S + 64, S + 320, b1, S + 20);
    k_colsum<<<4096, 256, 0, stream>>>(z1p, U2, 256, 16384);
    k_v2<<<49, 256, 0, stream>>>(U2, V2);

    // conv2 -> OUT
    k_convmm<2, 1><<<dim3(98, 4), 256, 0, stream>>>(wq2c, z1p, R2, T2, V2, S + 14, S + 20, OUT, 256, 2304);

    // range_norm2 -> z2 codes
    k_chstats<<<256, 256, 0, stream>>>(OUT, 256, S + 2368, S + 1856, S + 2112);
    k_finnorm<<<1, 256, 0, stream>>>(256, g2, b2, S + 2368, S + 1856, S + 2112, S + 1344, S + 1600, S + 23, scale_fix);
    k_code<2><<<dim3(7, 1, 64), 256, 0, stream>>>(OUT, z2c, S + 1344, S + 1600, b2, S + 23);
    k_colsum<<<3136, 256, 0, stream>>>(z2c, CZ, 256, NCOL);

    // conv3 -> d_out (fp32 NCHW)
    k_convmm<4, 0><<<dim3(98, 8), 256, 0, stream>>>(wq3c, z2c, R3, nullptr, CZ, S + 17, S + 23, out, 1024, 256);

    // range_norm3 stats + final fused residual add (in place in d_out)
    k_chstats<<<1024, 256, 0, stream>>>(out, 1024, S + 6720, S + 4672, S + 5696);
    k_finnorm<<<1, 256, 0, stream>>>(1024, g3, b3, S + 6720, S + 4672, S + 5696, S + 2624, S + 3648, S + 26, scale_fix);
    k_final<<<2048, 256, 0, stream>>>(x, out, S + 2624, S + 3648, b3, S, S + 26);
}